// Round 2
// baseline (175.223 us; speedup 1.0000x reference)
//
#include <hip/hip_runtime.h>
#include <hip/hip_bf16.h>

#define NNODES 8192
#define DIN 512
#define HD1 256
#define LATD 128

typedef __attribute__((ext_vector_type(4))) float f32x4;
typedef __attribute__((ext_vector_type(8))) short short8;

__device__ __forceinline__ float bf2f(ushort u){
  union { uint i; float f; } v; v.i = ((uint)u) << 16; return v.f;
}
__device__ __forceinline__ ushort f2bf(float f){
  union { float f; uint i; } v; v.f = f;
  uint i = v.i;
  i += 0x7FFFu + ((i >> 16) & 1u);
  return (ushort)(i >> 16);
}

// ---------------- f32 -> bf16 bulk convert (for x) ----------------

__global__ __launch_bounds__(256) void cvt_f32_bf16(const float* __restrict__ in,
                                                    ushort* __restrict__ out, int n4){
  int i = blockIdx.x * 256 + threadIdx.x;
  if (i >= n4) return;
  float4 v = ((const float4*)in)[i];
  uint2 w;
  w.x = (uint)f2bf(v.x) | ((uint)f2bf(v.y) << 16);
  w.y = (uint)f2bf(v.z) | ((uint)f2bf(v.w) << 16);
  ((uint2*)out)[i] = w;
}

// ---------------- CSR build ----------------

__global__ void count_deg(const int* __restrict__ ecol, int* __restrict__ counts, int E){
  int e = blockIdx.x * 256 + threadIdx.x;
  if (e < E) atomicAdd(&counts[ecol[e]], 1);
}

__global__ __launch_bounds__(1024) void scan_kernel(const int* __restrict__ counts, int* __restrict__ offsets){
  __shared__ int sd[1024];
  const int t = threadIdx.x;
  const int base = t * 8;
  int vals[8];
  int s = 0;
  #pragma unroll
  for (int i = 0; i < 8; ++i){ vals[i] = counts[base + i]; s += vals[i]; }
  sd[t] = s;
  __syncthreads();
  for (int off = 1; off < 1024; off <<= 1){
    int x = (t >= off) ? sd[t - off] : 0;
    __syncthreads();
    sd[t] += x;
    __syncthreads();
  }
  int ex = sd[t] - s;
  #pragma unroll
  for (int i = 0; i < 8; ++i){ offsets[base + i] = ex; ex += vals[i]; }
  if (t == 1023) offsets[8192] = ex;
}

__global__ void dis_kernel(const int* __restrict__ counts, float* __restrict__ dis){
  int v = blockIdx.x * 256 + threadIdx.x;
  // deg = in-degree + 2 (self-loop added in forward + again by gcn_norm)
  dis[v] = rsqrtf((float)(counts[v] + 2));
}

__global__ void fill_csr(const int* __restrict__ erow, const int* __restrict__ ecol,
                         const int* __restrict__ offsets, int* __restrict__ cursor,
                         int* __restrict__ csr, int E){
  int e = blockIdx.x * 256 + threadIdx.x;
  if (e >= E) return;
  int r = erow[e], c = ecol[e];
  int pos = atomicAdd(&cursor[c], 1);
  csr[offsets[c] + pos] = r;
}

// ---------------- GEMM: C[M,N] = A_bf16[M,K] @ B_f32[K,N] (+bias f32) ----------------
// 64x64 tile, BK=32, 4 waves of 32x32, mfma 16x16x32 bf16.
// OUT: 0 = bf16 C only, 1 = f32 C only, 2 = both.

template<bool BIAS, int OUT>
__global__ __launch_bounds__(256) void gemm_ab(const ushort* __restrict__ A,
    const float* __restrict__ B, const float* __restrict__ bias,
    ushort* __restrict__ Cb, float* __restrict__ Cf, int M, int N, int K)
{
  __shared__ ushort Al[64][40];
  __shared__ ushort Bl[64][40];   // stored transposed: Bl[n][k]
  const int t = threadIdx.x;
  const int n0 = blockIdx.x * 64, m0 = blockIdx.y * 64;
  const int wid = t >> 6, l = t & 63, lr = l & 15, lk = l >> 4;
  const int wm = (wid >> 1) * 32, wn = (wid & 1) * 32;
  f32x4 acc[2][2] = {};
  const int nkt = K >> 5;
  for (int kt = 0; kt < nkt; ++kt){
    {
      const int row = t >> 2, ch = t & 3;
      *(short8*)(&Al[row][ch * 8]) =
        *(const short8*)(A + (size_t)(m0 + row) * K + kt * 32 + ch * 8);
      const int kk = t >> 3, nn = (t & 7) * 8;
      const float* bp = B + (size_t)(kt * 32 + kk) * N + n0 + nn;
      float4 v0 = *(const float4*)bp;
      float4 v1 = *(const float4*)(bp + 4);
      Bl[nn + 0][kk] = f2bf(v0.x); Bl[nn + 1][kk] = f2bf(v0.y);
      Bl[nn + 2][kk] = f2bf(v0.z); Bl[nn + 3][kk] = f2bf(v0.w);
      Bl[nn + 4][kk] = f2bf(v1.x); Bl[nn + 5][kk] = f2bf(v1.y);
      Bl[nn + 6][kk] = f2bf(v1.z); Bl[nn + 7][kk] = f2bf(v1.w);
    }
    __syncthreads();
    short8 a0 = *(const short8*)(&Al[wm + lr][lk * 8]);
    short8 a1 = *(const short8*)(&Al[wm + 16 + lr][lk * 8]);
    short8 b0 = *(const short8*)(&Bl[wn + lr][lk * 8]);
    short8 b1 = *(const short8*)(&Bl[wn + 16 + lr][lk * 8]);
    acc[0][0] = __builtin_amdgcn_mfma_f32_16x16x32_bf16(a0, b0, acc[0][0], 0, 0, 0);
    acc[0][1] = __builtin_amdgcn_mfma_f32_16x16x32_bf16(a0, b1, acc[0][1], 0, 0, 0);
    acc[1][0] = __builtin_amdgcn_mfma_f32_16x16x32_bf16(a1, b0, acc[1][0], 0, 0, 0);
    acc[1][1] = __builtin_amdgcn_mfma_f32_16x16x32_bf16(a1, b1, acc[1][1], 0, 0, 0);
    __syncthreads();
  }
  #pragma unroll
  for (int mi = 0; mi < 2; ++mi){
    #pragma unroll
    for (int ni = 0; ni < 2; ++ni){
      const int row = m0 + wm + mi * 16 + lk * 4;
      const int col = n0 + wn + ni * 16 + lr;
      float bb = BIAS ? bias[col] : 0.f;
      #pragma unroll
      for (int r = 0; r < 4; ++r){
        float v = acc[mi][ni][r] + bb;
        if (OUT != 1) Cb[(size_t)(row + r) * N + col] = f2bf(v);
        if (OUT != 0) Cf[(size_t)(row + r) * N + col] = v;
      }
    }
  }
}

// ---------------- aggregation: out[v] = sum_e norm*h[r] + 2*dis[v]^2*h[v] + bias (opt relu) ----------------

template<int F, bool RELU>
__global__ __launch_bounds__(64) void agg_kernel(const ushort* __restrict__ h,
    const float* __restrict__ bias, const int* __restrict__ offsets,
    const int* __restrict__ csr, const float* __restrict__ dis,
    ushort* __restrict__ out)
{
  constexpr int EPT = F / 64;
  const int v = blockIdx.x;
  const int l = threadIdx.x;
  const float dv = dis[v];
  float acc[EPT];
  {
    const float ss = 2.f * dv * dv;
    const ushort* p = h + (size_t)v * F + l * EPT;
    if constexpr (EPT == 4){
      uint2 r = *(const uint2*)p;
      acc[0] = ss * bf2f((ushort)(r.x & 0xffff));
      acc[1] = ss * bf2f((ushort)(r.x >> 16));
      acc[2] = ss * bf2f((ushort)(r.y & 0xffff));
      acc[3] = ss * bf2f((ushort)(r.y >> 16));
    } else {
      uint r = *(const uint*)p;
      acc[0] = ss * bf2f((ushort)(r & 0xffff));
      acc[1] = ss * bf2f((ushort)(r >> 16));
    }
  }
  const int beg = offsets[v], end = offsets[v + 1];
  for (int e = beg; e < end; ++e){
    const int rsrc = csr[e];
    const float nr = dis[rsrc] * dv;
    const ushort* p = h + (size_t)rsrc * F + l * EPT;
    if constexpr (EPT == 4){
      uint2 r = *(const uint2*)p;
      acc[0] += nr * bf2f((ushort)(r.x & 0xffff));
      acc[1] += nr * bf2f((ushort)(r.x >> 16));
      acc[2] += nr * bf2f((ushort)(r.y & 0xffff));
      acc[3] += nr * bf2f((ushort)(r.y >> 16));
    } else {
      uint r = *(const uint*)p;
      acc[0] += nr * bf2f((ushort)(r & 0xffff));
      acc[1] += nr * bf2f((ushort)(r >> 16));
    }
  }
  ushort u[EPT];
  #pragma unroll
  for (int i = 0; i < EPT; ++i){
    float val = acc[i] + bias[l * EPT + i];
    if (RELU) val = fmaxf(val, 0.f);
    u[i] = f2bf(val);
  }
  ushort* o = out + (size_t)v * F + l * EPT;
  if constexpr (EPT == 4){
    uint2 w;
    w.x = (uint)u[0] | ((uint)u[1] << 16);
    w.y = (uint)u[2] | ((uint)u[3] << 16);
    *(uint2*)o = w;
  } else {
    *(uint*)o = (uint)u[0] | ((uint)u[1] << 16);
  }
}

// ---------------- adj = sigmoid(mu @ mu^T), 128x128 tiles, f32 out ----------------
// B = mu^T, so the B-fragment loads exactly like an A-fragment from row-major mu.

__global__ __launch_bounds__(512) void gemm5_kernel(const ushort* __restrict__ mu,
                                                    float* __restrict__ adj)
{
  __shared__ char lds[65536];
  const int t = threadIdx.x;
  const int bj = blockIdx.x, bi = blockIdx.y;
  {
    const int row = t >> 2, ch = t & 3;
    const char* srcA = (const char*)(mu + (size_t)(bi * 128 + row) * LATD);
    const char* srcB = (const char*)(mu + (size_t)(bj * 128 + row) * LATD);
    char* dA = lds + row * 256;
    char* dB = lds + 32768 + row * 256;
    #pragma unroll
    for (int i = 0; i < 4; ++i){
      const int kb = ch * 64 + i * 16;
      const int sk = kb ^ ((row & 7) << 4);
      *(short8*)(dA + sk) = *(const short8*)(srcA + kb);
      *(short8*)(dB + sk) = *(const short8*)(srcB + kb);
    }
  }
  __syncthreads();
  const int wid = t >> 6, l = t & 63, lr = l & 15, lk = l >> 4;
  const int wm = (wid >> 2) * 64, wn = (wid & 3) * 32;
  f32x4 acc[4][2] = {};
  #pragma unroll
  for (int ks = 0; ks < 4; ++ks){
    short8 a[4], b[2];
    const int kb = ks * 64 + lk * 16;
    #pragma unroll
    for (int mi = 0; mi < 4; ++mi){
      const int r = wm + mi * 16 + lr;
      a[mi] = *(const short8*)(lds + r * 256 + (kb ^ ((r & 7) << 4)));
    }
    #pragma unroll
    for (int ni = 0; ni < 2; ++ni){
      const int r = wn + ni * 16 + lr;
      b[ni] = *(const short8*)(lds + 32768 + r * 256 + (kb ^ ((r & 7) << 4)));
    }
    #pragma unroll
    for (int mi = 0; mi < 4; ++mi)
      #pragma unroll
      for (int ni = 0; ni < 2; ++ni)
        acc[mi][ni] = __builtin_amdgcn_mfma_f32_16x16x32_bf16(a[mi], b[ni], acc[mi][ni], 0, 0, 0);
  }
  __syncthreads();
  // epilogue in two 64-row halves: sigmoid f32 -> LDS [64][132] -> coalesced float4 stores
  float* ep = (float*)lds;
  const int myhalf = wid >> 2;
  #pragma unroll
  for (int h = 0; h < 2; ++h){
    if (myhalf == h){
      #pragma unroll
      for (int mi = 0; mi < 4; ++mi){
        #pragma unroll
        for (int ni = 0; ni < 2; ++ni){
          const int rl = mi * 16 + lk * 4;
          const int cc = wn + ni * 16 + lr;
          #pragma unroll
          for (int r = 0; r < 4; ++r){
            const float x = acc[mi][ni][r];
            ep[(rl + r) * 132 + cc] = 1.f / (1.f + __expf(-x));
          }
        }
      }
    }
    __syncthreads();
    #pragma unroll
    for (int p = 0; p < 4; ++p){
      const int rl = p * 16 + (t >> 5);
      const int c4 = (t & 31) * 4;
      float4 v = *(const float4*)(&ep[rl * 132 + c4]);
      *(float4*)(adj + (size_t)(bi * 128 + h * 64 + rl) * NNODES + bj * 128 + c4) = v;
    }
    __syncthreads();
  }
}

// ---------------- launch ----------------

extern "C" void kernel_launch(void* const* d_in, const int* in_sizes, int n_in,
                              void* d_out, int out_size, void* d_ws, size_t ws_size,
                              hipStream_t stream)
{
  const float* x    = (const float*)d_in[0];
  const int*   ei   = (const int*)d_in[1];
  const float* W1   = (const float*)d_in[2];
  const float* b1   = (const float*)d_in[3];
  const float* W2   = (const float*)d_in[4];
  const float* b2   = (const float*)d_in[5];
  const float* Wmu  = (const float*)d_in[6];
  const float* bmu  = (const float*)d_in[7];
  const float* Wlv  = (const float*)d_in[8];
  const float* blv  = (const float*)d_in[9];
  const int E = in_sizes[1] / 2;
  const int* erow = ei;
  const int* ecol = ei + E;

  char* ws = (char*)d_ws;
  int*    counts  = (int*)(ws);                  // 32KB
  int*    cursor  = (int*)(ws + 32768);          // 32KB
  int*    offsets = (int*)(ws + 65536);          // 8193 ints (36KB reserved)
  float*  dis     = (float*)(ws + 102400);       // 32KB
  int*    csr     = (int*)(ws + 135168);         // 1MB
  ushort* x_bf    = (ushort*)(ws + 1183744);     // 8MB  (8192x512 bf16)
  ushort* h1      = (ushort*)(ws + 9572352);     // 4MB  (8192x256)
  ushort* z1      = (ushort*)(ws + 13766656);    // 4MB
  ushort* h2      = (ushort*)(ws + 17960960);    // 2MB  (8192x128)
  ushort* z2      = (ushort*)(ws + 20058112);    // 2MB
  ushort* mu_bf   = (ushort*)(ws + 22155264);    // 2MB

  float* adj = (float*)d_out;
  float* mu  = adj + (size_t)NNODES * NNODES;
  float* lv  = mu + (size_t)NNODES * LATD;

  hipMemsetAsync(d_ws, 0, 65536, stream);  // counts + cursor
  count_deg<<<(E + 255) / 256, 256, 0, stream>>>(ecol, counts, E);
  scan_kernel<<<1, 1024, 0, stream>>>(counts, offsets);
  dis_kernel<<<NNODES / 256, 256, 0, stream>>>(counts, dis);
  fill_csr<<<(E + 255) / 256, 256, 0, stream>>>(erow, ecol, offsets, cursor, csr, E);

  // x -> bf16
  cvt_f32_bf16<<<(NNODES * DIN / 4 + 255) / 256, 256, 0, stream>>>(x, x_bf, NNODES * DIN / 4);

  // layer 1: h1 = x @ W1 ; z1 = relu(agg(h1) + b1)
  gemm_ab<false, 0><<<dim3(HD1 / 64, NNODES / 64), 256, 0, stream>>>(x_bf, W1, nullptr, h1, nullptr, NNODES, HD1, DIN);
  agg_kernel<HD1, true><<<NNODES, 64, 0, stream>>>(h1, b1, offsets, csr, dis, z1);

  // layer 2: h2 = z1 @ W2 ; z2 = agg(h2) + b2
  gemm_ab<false, 0><<<dim3(LATD / 64, NNODES / 64), 256, 0, stream>>>(z1, W2, nullptr, h2, nullptr, NNODES, LATD, HD1);
  agg_kernel<LATD, false><<<NNODES, 64, 0, stream>>>(h2, b2, offsets, csr, dis, z2);

  // mu (f32 out + bf16 copy) / logvar (f32 out)
  gemm_ab<true, 2><<<dim3(LATD / 64, NNODES / 64), 256, 0, stream>>>(z2, Wmu, bmu, mu_bf, mu, NNODES, LATD, LATD);
  gemm_ab<true, 1><<<dim3(LATD / 64, NNODES / 64), 256, 0, stream>>>(z2, Wlv, blv, nullptr, lv, NNODES, LATD, LATD);

  // adj = sigmoid(mu @ mu^T)
  gemm5_kernel<<<dim3(NNODES / 128, NNODES / 128), 512, 0, stream>>>(mu_bf, adj);
}

// Round 3
// 164.510 us; speedup vs baseline: 1.0651x; 1.0651x over previous
//
#include <hip/hip_runtime.h>
#include <hip/hip_bf16.h>

#define NNODES 8192
#define DIN 512
#define HD1 256
#define LATD 128

typedef __attribute__((ext_vector_type(4))) float f32x4;
typedef __attribute__((ext_vector_type(8))) short short8;

__device__ __forceinline__ float bf2f(ushort u){
  union { uint i; float f; } v; v.i = ((uint)u) << 16; return v.f;
}
__device__ __forceinline__ ushort f2bf(float f){
  union { float f; uint i; } v; v.f = f;
  uint i = v.i;
  i += 0x7FFFu + ((i >> 16) & 1u);
  return (ushort)(i >> 16);
}

// ---------------- f32 -> bf16 bulk convert (for x) ----------------

__global__ __launch_bounds__(256) void cvt_f32_bf16(const float* __restrict__ in,
                                                    ushort* __restrict__ out, int n4){
  int i = blockIdx.x * 256 + threadIdx.x;
  if (i >= n4) return;
  float4 v = ((const float4*)in)[i];
  uint2 w;
  w.x = (uint)f2bf(v.x) | ((uint)f2bf(v.y) << 16);
  w.y = (uint)f2bf(v.z) | ((uint)f2bf(v.w) << 16);
  ((uint2*)out)[i] = w;
}

// ---------------- CSR build ----------------

__global__ void count_deg(const int* __restrict__ ecol, int* __restrict__ counts, int E){
  int e = blockIdx.x * 256 + threadIdx.x;
  if (e < E) atomicAdd(&counts[ecol[e]], 1);
}

// scan + dis in one kernel
__global__ __launch_bounds__(1024) void scan_kernel(const int* __restrict__ counts,
                                                    int* __restrict__ offsets,
                                                    float* __restrict__ dis){
  __shared__ int sd[1024];
  const int t = threadIdx.x;
  const int base = t * 8;
  int vals[8];
  int s = 0;
  #pragma unroll
  for (int i = 0; i < 8; ++i){ vals[i] = counts[base + i]; s += vals[i]; }
  sd[t] = s;
  __syncthreads();
  for (int off = 1; off < 1024; off <<= 1){
    int x = (t >= off) ? sd[t - off] : 0;
    __syncthreads();
    sd[t] += x;
    __syncthreads();
  }
  int ex = sd[t] - s;
  #pragma unroll
  for (int i = 0; i < 8; ++i){
    offsets[base + i] = ex; ex += vals[i];
    // deg = in-degree + 2 (self-loop added in forward + again by gcn_norm)
    dis[base + i] = rsqrtf((float)(vals[i] + 2));
  }
  if (t == 1023) offsets[8192] = ex;
}

__global__ void fill_csr(const int* __restrict__ erow, const int* __restrict__ ecol,
                         const int* __restrict__ offsets, int* __restrict__ cursor,
                         int* __restrict__ csr, int E){
  int e = blockIdx.x * 256 + threadIdx.x;
  if (e >= E) return;
  int r = erow[e], c = ecol[e];
  int pos = atomicAdd(&cursor[c], 1);
  csr[offsets[c] + pos] = r;
}

// ---------------- GEMM: C[M,N] = A_bf16[M,K] @ B_f32[K,N] ----------------
// 64x64 tile, BK=32, 4 waves of 32x32, mfma 16x16x32 bf16. bf16 C out.

__global__ __launch_bounds__(256) void gemm_ab(const ushort* __restrict__ A,
    const float* __restrict__ B, ushort* __restrict__ Cb, int N, int K)
{
  __shared__ ushort Al[64][40];
  __shared__ ushort Bl[64][40];   // stored transposed: Bl[n][k]
  const int t = threadIdx.x;
  const int n0 = blockIdx.x * 64, m0 = blockIdx.y * 64;
  const int wid = t >> 6, l = t & 63, lr = l & 15, lk = l >> 4;
  const int wm = (wid >> 1) * 32, wn = (wid & 1) * 32;
  f32x4 acc[2][2] = {};
  const int nkt = K >> 5;
  for (int kt = 0; kt < nkt; ++kt){
    {
      const int row = t >> 2, ch = t & 3;
      *(short8*)(&Al[row][ch * 8]) =
        *(const short8*)(A + (size_t)(m0 + row) * K + kt * 32 + ch * 8);
      const int kk = t >> 3, nn = (t & 7) * 8;
      const float* bp = B + (size_t)(kt * 32 + kk) * N + n0 + nn;
      float4 v0 = *(const float4*)bp;
      float4 v1 = *(const float4*)(bp + 4);
      Bl[nn + 0][kk] = f2bf(v0.x); Bl[nn + 1][kk] = f2bf(v0.y);
      Bl[nn + 2][kk] = f2bf(v0.z); Bl[nn + 3][kk] = f2bf(v0.w);
      Bl[nn + 4][kk] = f2bf(v1.x); Bl[nn + 5][kk] = f2bf(v1.y);
      Bl[nn + 6][kk] = f2bf(v1.z); Bl[nn + 7][kk] = f2bf(v1.w);
    }
    __syncthreads();
    short8 a0 = *(const short8*)(&Al[wm + lr][lk * 8]);
    short8 a1 = *(const short8*)(&Al[wm + 16 + lr][lk * 8]);
    short8 b0 = *(const short8*)(&Bl[wn + lr][lk * 8]);
    short8 b1 = *(const short8*)(&Bl[wn + 16 + lr][lk * 8]);
    acc[0][0] = __builtin_amdgcn_mfma_f32_16x16x32_bf16(a0, b0, acc[0][0], 0, 0, 0);
    acc[0][1] = __builtin_amdgcn_mfma_f32_16x16x32_bf16(a0, b1, acc[0][1], 0, 0, 0);
    acc[1][0] = __builtin_amdgcn_mfma_f32_16x16x32_bf16(a1, b0, acc[1][0], 0, 0, 0);
    acc[1][1] = __builtin_amdgcn_mfma_f32_16x16x32_bf16(a1, b1, acc[1][1], 0, 0, 0);
    __syncthreads();
  }
  #pragma unroll
  for (int mi = 0; mi < 2; ++mi){
    #pragma unroll
    for (int ni = 0; ni < 2; ++ni){
      const int row = m0 + wm + mi * 16 + lk * 4;
      const int col = n0 + wn + ni * 16 + lr;
      #pragma unroll
      for (int r = 0; r < 4; ++r)
        Cb[(size_t)(row + r) * N + col] = f2bf(acc[mi][ni][r]);
    }
  }
}

// ---------------- fused mu/logvar GEMM: K=N=128, block-uniform B select ----------------
// grid.x = 4 (cols 0..255); cols<128 -> mu (f32 + bf16), cols>=128 -> logvar (f32).

__global__ __launch_bounds__(256) void gemm_mulv(const ushort* __restrict__ A,
    const float* __restrict__ Wmu, const float* __restrict__ bmu,
    const float* __restrict__ Wlv, const float* __restrict__ blv,
    float* __restrict__ mu, ushort* __restrict__ mu_bf, float* __restrict__ lv)
{
  __shared__ ushort Al[64][40];
  __shared__ ushort Bl[64][40];
  const int t = threadIdx.x;
  const int gn0 = blockIdx.x * 64, m0 = blockIdx.y * 64;
  const bool is_mu = gn0 < LATD;
  const float* B = is_mu ? Wmu : Wlv;
  const float* bias = is_mu ? bmu : blv;
  const int n0 = gn0 & (LATD - 1);
  const int wid = t >> 6, l = t & 63, lr = l & 15, lk = l >> 4;
  const int wm = (wid >> 1) * 32, wn = (wid & 1) * 32;
  f32x4 acc[2][2] = {};
  for (int kt = 0; kt < LATD / 32; ++kt){
    {
      const int row = t >> 2, ch = t & 3;
      *(short8*)(&Al[row][ch * 8]) =
        *(const short8*)(A + (size_t)(m0 + row) * LATD + kt * 32 + ch * 8);
      const int kk = t >> 3, nn = (t & 7) * 8;
      const float* bp = B + (size_t)(kt * 32 + kk) * LATD + n0 + nn;
      float4 v0 = *(const float4*)bp;
      float4 v1 = *(const float4*)(bp + 4);
      Bl[nn + 0][kk] = f2bf(v0.x); Bl[nn + 1][kk] = f2bf(v0.y);
      Bl[nn + 2][kk] = f2bf(v0.z); Bl[nn + 3][kk] = f2bf(v0.w);
      Bl[nn + 4][kk] = f2bf(v1.x); Bl[nn + 5][kk] = f2bf(v1.y);
      Bl[nn + 6][kk] = f2bf(v1.z); Bl[nn + 7][kk] = f2bf(v1.w);
    }
    __syncthreads();
    short8 a0 = *(const short8*)(&Al[wm + lr][lk * 8]);
    short8 a1 = *(const short8*)(&Al[wm + 16 + lr][lk * 8]);
    short8 b0 = *(const short8*)(&Bl[wn + lr][lk * 8]);
    short8 b1 = *(const short8*)(&Bl[wn + 16 + lr][lk * 8]);
    acc[0][0] = __builtin_amdgcn_mfma_f32_16x16x32_bf16(a0, b0, acc[0][0], 0, 0, 0);
    acc[0][1] = __builtin_amdgcn_mfma_f32_16x16x32_bf16(a0, b1, acc[0][1], 0, 0, 0);
    acc[1][0] = __builtin_amdgcn_mfma_f32_16x16x32_bf16(a1, b0, acc[1][0], 0, 0, 0);
    acc[1][1] = __builtin_amdgcn_mfma_f32_16x16x32_bf16(a1, b1, acc[1][1], 0, 0, 0);
    __syncthreads();
  }
  #pragma unroll
  for (int mi = 0; mi < 2; ++mi){
    #pragma unroll
    for (int ni = 0; ni < 2; ++ni){
      const int row = m0 + wm + mi * 16 + lk * 4;
      const int col = n0 + wn + ni * 16 + lr;
      float bb = bias[col];
      #pragma unroll
      for (int r = 0; r < 4; ++r){
        float v = acc[mi][ni][r] + bb;
        if (is_mu){
          mu[(size_t)(row + r) * LATD + col] = v;
          mu_bf[(size_t)(row + r) * LATD + col] = f2bf(v);
        } else {
          lv[(size_t)(row + r) * LATD + col] = v;
        }
      }
    }
  }
}

// ---------------- aggregation: out[v] = sum_e norm*h[r] + 2*dis[v]^2*h[v] + bias ----------------
// 4 waves/block, one node per wave; (csr,dis) prefetched 64-wide and shuffle-broadcast.

template<int F, bool RELU>
__global__ __launch_bounds__(256) void agg_kernel(const ushort* __restrict__ h,
    const float* __restrict__ bias, const int* __restrict__ offsets,
    const int* __restrict__ csr, const float* __restrict__ dis,
    ushort* __restrict__ out)
{
  constexpr int EPT = F / 64;
  const int l = threadIdx.x & 63;
  const int v = blockIdx.x * 4 + (threadIdx.x >> 6);
  const float dv = dis[v];
  float acc[EPT];
  {
    const float ss = 2.f * dv * dv;
    const ushort* p = h + (size_t)v * F + l * EPT;
    if constexpr (EPT == 4){
      uint2 r = *(const uint2*)p;
      acc[0] = ss * bf2f((ushort)(r.x & 0xffff));
      acc[1] = ss * bf2f((ushort)(r.x >> 16));
      acc[2] = ss * bf2f((ushort)(r.y & 0xffff));
      acc[3] = ss * bf2f((ushort)(r.y >> 16));
    } else {
      uint r = *(const uint*)p;
      acc[0] = ss * bf2f((ushort)(r & 0xffff));
      acc[1] = ss * bf2f((ushort)(r >> 16));
    }
  }
  const int beg = offsets[v], end = offsets[v + 1];
  for (int base = beg; base < end; base += 64){
    const int cnt = min(64, end - base);
    const bool live = (base + l) < end;
    int idx = live ? csr[base + l] : 0;
    float dn = live ? dis[idx] : 0.f;
    for (int e = 0; e < cnt; ++e){
      const int rsrc = __shfl(idx, e);
      const float nr = __shfl(dn, e) * dv;
      const ushort* p = h + (size_t)rsrc * F + l * EPT;
      if constexpr (EPT == 4){
        uint2 r = *(const uint2*)p;
        acc[0] += nr * bf2f((ushort)(r.x & 0xffff));
        acc[1] += nr * bf2f((ushort)(r.x >> 16));
        acc[2] += nr * bf2f((ushort)(r.y & 0xffff));
        acc[3] += nr * bf2f((ushort)(r.y >> 16));
      } else {
        uint r = *(const uint*)p;
        acc[0] += nr * bf2f((ushort)(r & 0xffff));
        acc[1] += nr * bf2f((ushort)(r >> 16));
      }
    }
  }
  ushort u[EPT];
  #pragma unroll
  for (int i = 0; i < EPT; ++i){
    float val = acc[i] + bias[l * EPT + i];
    if (RELU) val = fmaxf(val, 0.f);
    u[i] = f2bf(val);
  }
  ushort* o = out + (size_t)v * F + l * EPT;
  if constexpr (EPT == 4){
    uint2 w;
    w.x = (uint)u[0] | ((uint)u[1] << 16);
    w.y = (uint)u[2] | ((uint)u[3] << 16);
    *(uint2*)o = w;
  } else {
    *(uint*)o = (uint)u[0] | ((uint)u[1] << 16);
  }
}

// ---------------- adj = sigmoid(mu @ mu^T), 128x128 tiles, f32 out ----------------
// B = mu^T, so the B-fragment loads exactly like an A-fragment from row-major mu.
// Direct fragment stores: one inst = 4 rows x 64B contiguous -> full HBM write BW.

__global__ __launch_bounds__(512) void gemm5_kernel(const ushort* __restrict__ mu,
                                                    float* __restrict__ adj)
{
  __shared__ char lds[65536];
  const int t = threadIdx.x;
  const int bj = blockIdx.x, bi = blockIdx.y;
  {
    const int row = t >> 2, ch = t & 3;
    const char* srcA = (const char*)(mu + (size_t)(bi * 128 + row) * LATD);
    const char* srcB = (const char*)(mu + (size_t)(bj * 128 + row) * LATD);
    char* dA = lds + row * 256;
    char* dB = lds + 32768 + row * 256;
    #pragma unroll
    for (int i = 0; i < 4; ++i){
      const int kb = ch * 64 + i * 16;
      const int sk = kb ^ ((row & 7) << 4);
      *(short8*)(dA + sk) = *(const short8*)(srcA + kb);
      *(short8*)(dB + sk) = *(const short8*)(srcB + kb);
    }
  }
  __syncthreads();
  const int wid = t >> 6, l = t & 63, lr = l & 15, lk = l >> 4;
  const int wm = (wid >> 2) * 64, wn = (wid & 3) * 32;
  f32x4 acc[4][2] = {};
  #pragma unroll
  for (int ks = 0; ks < 4; ++ks){
    short8 a[4], b[2];
    const int kb = ks * 64 + lk * 16;
    #pragma unroll
    for (int mi = 0; mi < 4; ++mi){
      const int r = wm + mi * 16 + lr;
      a[mi] = *(const short8*)(lds + r * 256 + (kb ^ ((r & 7) << 4)));
    }
    #pragma unroll
    for (int ni = 0; ni < 2; ++ni){
      const int r = wn + ni * 16 + lr;
      b[ni] = *(const short8*)(lds + 32768 + r * 256 + (kb ^ ((r & 7) << 4)));
    }
    #pragma unroll
    for (int mi = 0; mi < 4; ++mi)
      #pragma unroll
      for (int ni = 0; ni < 2; ++ni)
        acc[mi][ni] = __builtin_amdgcn_mfma_f32_16x16x32_bf16(a[mi], b[ni], acc[mi][ni], 0, 0, 0);
  }
  // direct store epilogue: sigmoid on the fly
  float* orow = adj + (size_t)(bi * 128 + wm + lk * 4) * NNODES + bj * 128 + wn + lr;
  #pragma unroll
  for (int mi = 0; mi < 4; ++mi){
    #pragma unroll
    for (int ni = 0; ni < 2; ++ni){
      #pragma unroll
      for (int r = 0; r < 4; ++r){
        const float x = acc[mi][ni][r];
        orow[(size_t)(mi * 16 + r) * NNODES + ni * 16] = 1.f / (1.f + __expf(-x));
      }
    }
  }
}

// ---------------- launch ----------------

extern "C" void kernel_launch(void* const* d_in, const int* in_sizes, int n_in,
                              void* d_out, int out_size, void* d_ws, size_t ws_size,
                              hipStream_t stream)
{
  const float* x    = (const float*)d_in[0];
  const int*   ei   = (const int*)d_in[1];
  const float* W1   = (const float*)d_in[2];
  const float* b1   = (const float*)d_in[3];
  const float* W2   = (const float*)d_in[4];
  const float* b2   = (const float*)d_in[5];
  const float* Wmu  = (const float*)d_in[6];
  const float* bmu  = (const float*)d_in[7];
  const float* Wlv  = (const float*)d_in[8];
  const float* blv  = (const float*)d_in[9];
  const int E = in_sizes[1] / 2;
  const int* erow = ei;
  const int* ecol = ei + E;

  char* ws = (char*)d_ws;
  int*    counts  = (int*)(ws);                  // 32KB
  int*    cursor  = (int*)(ws + 32768);          // 32KB
  int*    offsets = (int*)(ws + 65536);          // 8193 ints (36KB reserved)
  float*  dis     = (float*)(ws + 102400);       // 32KB
  int*    csr     = (int*)(ws + 135168);         // 1MB
  ushort* x_bf    = (ushort*)(ws + 1183744);     // 8MB  (8192x512 bf16)
  ushort* h1      = (ushort*)(ws + 9572352);     // 4MB  (8192x256)
  ushort* z1      = (ushort*)(ws + 13766656);    // 4MB
  ushort* h2      = (ushort*)(ws + 17960960);    // 2MB  (8192x128)
  ushort* z2      = (ushort*)(ws + 20058112);    // 2MB
  ushort* mu_bf   = (ushort*)(ws + 22155264);    // 2MB

  float* adj = (float*)d_out;
  float* mu  = adj + (size_t)NNODES * NNODES;
  float* lv  = mu + (size_t)NNODES * LATD;

  hipMemsetAsync(d_ws, 0, 65536, stream);  // counts + cursor
  count_deg<<<(E + 255) / 256, 256, 0, stream>>>(ecol, counts, E);
  scan_kernel<<<1, 1024, 0, stream>>>(counts, offsets, dis);
  fill_csr<<<(E + 255) / 256, 256, 0, stream>>>(erow, ecol, offsets, cursor, csr, E);

  // x -> bf16
  cvt_f32_bf16<<<(NNODES * DIN / 4 + 255) / 256, 256, 0, stream>>>(x, x_bf, NNODES * DIN / 4);

  // layer 1: h1 = x @ W1 ; z1 = relu(agg(h1) + b1)
  gemm_ab<<<dim3(HD1 / 64, NNODES / 64), 256, 0, stream>>>(x_bf, W1, h1, HD1, DIN);
  agg_kernel<HD1, true><<<NNODES / 4, 256, 0, stream>>>(h1, b1, offsets, csr, dis, z1);

  // layer 2: h2 = z1 @ W2 ; z2 = agg(h2) + b2
  gemm_ab<<<dim3(LATD / 64, NNODES / 64), 256, 0, stream>>>(z1, W2, h2, LATD, HD1);
  agg_kernel<LATD, false><<<NNODES / 4, 256, 0, stream>>>(h2, b2, offsets, csr, dis, z2);

  // mu (f32 + bf16) / logvar (f32) fused
  gemm_mulv<<<dim3(2 * LATD / 64, NNODES / 64), 256, 0, stream>>>(z2, Wmu, bmu, Wlv, blv, mu, mu_bf, lv);

  // adj = sigmoid(mu @ mu^T)
  gemm5_kernel<<<dim3(NNODES / 128, NNODES / 128), 512, 0, stream>>>(mu_bf, adj);
}